// Round 6
// baseline (263.984 us; speedup 1.0000x reference)
//
#include <hip/hip_runtime.h>
#include <stdint.h>
#include <stddef.h>

#define N_TOK 4096
#define DM    1024
#define NHEAD 16
#define HD    64

typedef __attribute__((ext_vector_type(8)))  short bf16x8;
typedef __attribute__((ext_vector_type(4)))  short bf16x4;
typedef __attribute__((ext_vector_type(4)))  float f32x4;
typedef __attribute__((ext_vector_type(16))) float f32x16;

static __device__ __forceinline__ float bf2f(short u) {
  union { unsigned int i; float f; } c;
  c.i = ((unsigned int)(unsigned short)u) << 16;
  return c.f;
}
static __device__ __forceinline__ unsigned short f2bf(float f) {
  union { float f; unsigned int i; } c; c.f = f;
  unsigned int x = c.i;
  return (unsigned short)((x + 0x7fffu + ((x >> 16) & 1u)) >> 16);
}
static __device__ __forceinline__ unsigned int cvtpk(float lo, float hi) {
  unsigned int d;
  asm("v_cvt_pk_bf16_f32 %0, %1, %2" : "=v"(d) : "v"(lo), "v"(hi));
  return d;
}
static __device__ __forceinline__ void plswap(unsigned int& a, unsigned int& b) {
  asm("v_permlane32_swap_b32 %0, %1" : "+v"(a), "+v"(b));
}
#if __has_builtin(__builtin_amdgcn_exp2f)
#define EXP2(x) __builtin_amdgcn_exp2f(x)
#else
#define EXP2(x) exp2f(x)
#endif
// async global->LDS, 16B/lane; LDS dest wave-uniform base (HW adds lane*16)
static __device__ __forceinline__ void gload16(const void* g, void* l) {
  __builtin_amdgcn_global_load_lds(
      (const __attribute__((address_space(1))) unsigned int*)g,
      (__attribute__((address_space(3))) unsigned int*)l, 16, 0, 0);
}

// ---------------- fused fp32 -> bf16 conversion (all 7 tensors, 1 launch) ----------------
struct Cvt7 { const float* s[7]; unsigned short* d[7]; };
__global__ void cvt_all(Cvt7 a) {
  int u0 = blockIdx.x << 10;              // 1024 units per block, uniform segment
  int seg, off;
  if (u0 < 1572864) { seg = u0 >> 19; off = u0 & 524287; }
  else { int j = u0 - 1572864; seg = 3 + (j >> 17); off = j & 131071; }
  const float* s = a.s[seg];
  unsigned short* dd = a.d[seg];
  int t = off + threadIdx.x;
#pragma unroll
  for (int j = 0; j < 4; ++j, t += 256) {
    const f32x4* sp = (const f32x4*)(s + (size_t)t * 8);
    f32x4 x = sp[0], y = sp[1];
    bf16x8 o;
    o[0] = (short)f2bf(x[0]); o[1] = (short)f2bf(x[1]);
    o[2] = (short)f2bf(x[2]); o[3] = (short)f2bf(x[3]);
    o[4] = (short)f2bf(y[0]); o[5] = (short)f2bf(y[1]);
    o[6] = (short)f2bf(y[2]); o[7] = (short)f2bf(y[3]);
    *(bf16x8*)(dd + (size_t)t * 8) = o;
  }
}

// ---------------- GEMM core: C = A @ W^T + bias, (MI*32)M x 128N tile, dbuf ----------------
// modes: 0 = bf16 row-major out; 1 = f32 row-major out;
//        2 = per-head RMSNorm -> Kn[h][n][64] bf16;  3 = transpose -> Vt[h][d][n] bf16
template <int MI>
static __device__ __forceinline__ void gemm_core(
    const unsigned short* __restrict__ A,
    const unsigned short* __restrict__ W,
    const float* __restrict__ bias,
    unsigned short* __restrict__ Cb,
    float* __restrict__ Cf,
    const float* __restrict__ nw,
    int Nn, int K, int mode, int m0, int n0)
{
  __shared__ __align__(16) unsigned short At[2][MI * 1024];  // (MI*32) x 32
  __shared__ __align__(16) unsigned short Wt[2][128 * 32];
  const int tid  = threadIdx.x;
  const int wid  = tid >> 6, lane = tid & 63;
  const int lm   = lane & 15, lg = lane >> 4;
  const int wm   = (wid >> 1) * (MI * 16), wn = (wid & 1) * 64;
  const int CPW  = (MI * 2 + 8) / 4;       // chunks per wave

  f32x4 acc[MI][4];
#pragma unroll
  for (int i = 0; i < MI; ++i)
#pragma unroll
    for (int j = 0; j < 4; ++j) acc[i][j] = f32x4{0.f, 0.f, 0.f, 0.f};

  auto stage = [&](int b, int k0) {
#pragma unroll
    for (int i = 0; i < CPW; ++i) {
      int c = wid * CPW + i;
      if (c < MI * 2)
        gload16(A + (size_t)(m0 + c * 16 + (lane >> 2)) * K + k0 + (lane & 3) * 8,
                (char*)At + b * (MI * 2048) + c * 1024);
      else
        gload16(W + (size_t)(n0 + (c - MI * 2) * 16 + (lane >> 2)) * K + k0 + (lane & 3) * 8,
                (char*)Wt + b * 8192 + (c - MI * 2) * 1024);
    }
  };

  const int nk = K >> 5;
  stage(0, 0);
  __syncthreads();
  for (int kt = 0; kt < nk; ++kt) {
    const int cur = kt & 1;
    if (kt + 1 < nk) stage(cur ^ 1, (kt + 1) << 5);

    bf16x8 af[MI], bfr[4];
#pragma unroll
    for (int mi = 0; mi < MI; ++mi)
      af[mi] = *(const bf16x8*)&At[cur][(wm + mi * 16 + lm) * 32 + lg * 8];
#pragma unroll
    for (int ni = 0; ni < 4; ++ni)
      bfr[ni] = *(const bf16x8*)&Wt[cur][(wn + ni * 16 + lm) * 32 + lg * 8];
    __builtin_amdgcn_s_setprio(1);
#pragma unroll
    for (int mi = 0; mi < MI; ++mi)
#pragma unroll
      for (int ni = 0; ni < 4; ++ni)
        acc[mi][ni] = __builtin_amdgcn_mfma_f32_16x16x32_bf16(
            af[mi], bfr[ni], acc[mi][ni], 0, 0, 0);
    __builtin_amdgcn_s_setprio(0);
    __syncthreads();
  }

  float bv[4];
#pragma unroll
  for (int ni = 0; ni < 4; ++ni) bv[ni] = bias[n0 + wn + ni * 16 + lm];

  if (mode <= 1) {
#pragma unroll
    for (int mi = 0; mi < MI; ++mi)
#pragma unroll
      for (int ni = 0; ni < 4; ++ni) {
        int n = n0 + wn + ni * 16 + lm;
#pragma unroll
        for (int r = 0; r < 4; ++r) {
          int m = m0 + wm + mi * 16 + lg * 4 + r;
          float v = acc[mi][ni][r] + bv[ni];
          if (mode == 1) Cf[(size_t)m * Nn + n] = v;
          else           Cb[(size_t)m * Nn + n] = f2bf(v);
        }
      }
  } else if (mode == 2) {
    // K path: wave's 64 cols = one full head; fused RMSNorm over d
    const int h = (n0 + wn) >> 6;
    float w_[4];
#pragma unroll
    for (int ni = 0; ni < 4; ++ni) w_[ni] = nw[ni * 16 + lm];
#pragma unroll
    for (int mi = 0; mi < MI; ++mi) {
      float t[4][4], ssq[4];
#pragma unroll
      for (int ni = 0; ni < 4; ++ni)
#pragma unroll
        for (int r = 0; r < 4; ++r) t[ni][r] = acc[mi][ni][r] + bv[ni];
#pragma unroll
      for (int r = 0; r < 4; ++r)
        ssq[r] = t[0][r]*t[0][r] + t[1][r]*t[1][r] + t[2][r]*t[2][r] + t[3][r]*t[3][r];
#pragma unroll
      for (int r = 0; r < 4; ++r) {
        ssq[r] += __shfl_xor(ssq[r], 1);
        ssq[r] += __shfl_xor(ssq[r], 2);
        ssq[r] += __shfl_xor(ssq[r], 4);
        ssq[r] += __shfl_xor(ssq[r], 8);
      }
#pragma unroll
      for (int r = 0; r < 4; ++r) {
        float iv = rsqrtf(ssq[r] * (1.f / 64.f) + 1e-5f);
        int n_ = m0 + wm + mi * 16 + lg * 4 + r;
#pragma unroll
        for (int ni = 0; ni < 4; ++ni) {
          int d = ni * 16 + lm;
          Cb[(size_t)h * (N_TOK * HD) + (size_t)n_ * HD + d] = f2bf(t[ni][r] * w_[ni] * iv);
        }
      }
    }
  } else {
    // V path: transpose to Vt[h][d][n]
    const int h = (n0 + wn) >> 6;
#pragma unroll
    for (int mi = 0; mi < MI; ++mi)
#pragma unroll
      for (int ni = 0; ni < 4; ++ni) {
        int d  = ni * 16 + lm;
        int nb = m0 + wm + mi * 16 + lg * 4;
        bf16x4 o;
#pragma unroll
        for (int r = 0; r < 4; ++r) o[r] = (short)f2bf(acc[mi][ni][r] + bv[ni]);
        *(bf16x4*)&Cb[(size_t)h * (HD * N_TOK) + (size_t)d * N_TOK + nb] = o;
      }
  }
}

// fused QKV projections: grid (8, 32, 3), 128x128 tiles, z selects {q,k,v}
__global__ __launch_bounds__(256, 3) void qkv_gemm(
    const unsigned short* __restrict__ a0, const unsigned short* __restrict__ a1,
    const unsigned short* __restrict__ a2,
    const unsigned short* __restrict__ w0, const unsigned short* __restrict__ w1,
    const unsigned short* __restrict__ w2,
    const float* __restrict__ b0, const float* __restrict__ b1,
    const float* __restrict__ b2,
    unsigned short* __restrict__ o0, unsigned short* __restrict__ o1,
    unsigned short* __restrict__ o2,
    const float* __restrict__ knw)
{
  const int z = blockIdx.z;
  const unsigned short* A = (z == 0) ? a0 : (z == 1) ? a1 : a2;
  const unsigned short* W = (z == 0) ? w0 : (z == 1) ? w1 : w2;
  const float* B          = (z == 0) ? b0 : (z == 1) ? b1 : b2;
  unsigned short* O       = (z == 0) ? o0 : (z == 1) ? o1 : o2;
  const int mode          = (z == 0) ? 0 : (z == 1) ? 2 : 3;
  gemm_core<4>(A, W, B, O, nullptr, knw, DM, DM, mode,
               blockIdx.y * 128, blockIdx.x * 128);
}

// out-projection: f32 out, 64x128 tiles, grid (8, 64)
__global__ __launch_bounds__(256, 4) void out_gemm(
    const unsigned short* __restrict__ A, const unsigned short* __restrict__ W,
    const float* __restrict__ bias, float* __restrict__ Cf)
{
  gemm_core<2>(A, W, bias, nullptr, Cf, nullptr, DM, DM, 1,
               blockIdx.y * 64, blockIdx.x * 128);
}

// ---------------- fused RMSNorm(Q) + attention: swapped-QK 32x32, in-block kv-split,
//                  K in LDS (4 bufs, tile-pair barriers), V direct-to-register ----------
// grid 512 blocks x 512 threads. 8 waves = 2 kv-groups x 4 waves. q-tile 128/block.
// Softmax has NO max-shift: uniform scale cancels in P/sum(P); exp2 args bounded (<=93).
__global__ __launch_bounds__(512, 4) void attn_kernel(
    const unsigned short* __restrict__ qb,   // (n, 1024) bf16
    const unsigned short* __restrict__ kn,   // Kn[h][kv][64] bf16, normalized
    const unsigned short* __restrict__ vt,   // Vt[h][d][kv] bf16
    const float* __restrict__ wq,            // q_norm_w[64]
    unsigned short* __restrict__ ob)         // (n, 1024) bf16
{
  // [group][buf0..3][64x64 bf16 tile]: 64 KB
  __shared__ __align__(16) unsigned short Ksm[2][4][4096];

  // XCD-aware decode: XCD x owns heads {2x, 2x+1}
  const int wg   = blockIdx.x;
  const int x_   = wg & 7, rest = wg >> 3;     // rest 0..63
  const int h    = x_ * 2 + (rest & 1);
  const int qt   = rest >> 1;                  // 0..31
  const int tid  = threadIdx.x;
  const int wid  = tid >> 6, lane = tid & 63;
  const int g    = wid >> 2, wv = wid & 3;
  const int l31  = lane & 31, hi = lane >> 5;
  const int sl   = l31 & 7;
  const int qbase = qt * 128 + wv * 32;

  // ---- Q fragments, RMSNorm fused, scaled by log2(e) ----
  bf16x8 qf[4];
  {
    const unsigned short* qp = qb + (size_t)(qbase + l31) * DM + h * HD + hi * 8;
    float qv[32]; float ss = 0.f;
#pragma unroll
    for (int s = 0; s < 4; ++s) {
      bf16x8 raw = *(const bf16x8*)(qp + s * 16);
#pragma unroll
      for (int j = 0; j < 8; ++j) { float f = bf2f(raw[j]); qv[s*8+j] = f; ss += f*f; }
    }
    ss += __shfl_xor(ss, 32);
    float inv = rsqrtf(ss * (1.f / 64.f) + 1e-5f) * 1.44269504f;
#pragma unroll
    for (int s = 0; s < 4; ++s)
#pragma unroll
      for (int j = 0; j < 8; ++j)
        qf[s][j] = (short)f2bf(qv[s*8+j] * wq[s*16 + hi*8 + j] * inv);
  }

  int slot[4];
#pragma unroll
  for (int x = 0; x < 4; ++x) slot[x] = (((2*x + hi) ^ sl) << 4);
  const char* kbase = (const char*)Ksm + g * 32768 + l31 * 128;

  // K staging: per wave 2 chunks of 1KB per tile (pre-swizzled global source)
  const char* kgsrc[2];
  char*       kldst[2];
  {
    const char* knb = (const char*)kn + (size_t)h * (N_TOK * HD * 2)
                    + (size_t)g * 2048 * 128;
#pragma unroll
    for (int i = 0; i < 2; ++i) {
      int c    = wv * 2 + i;            // chunk 0..7
      int off  = c * 1024 + lane * 16;
      int row  = off >> 7;              // kv-local row 0..63
      int scol = (off & 127) ^ ((row & 7) << 4);
      kgsrc[i] = knb + (size_t)row * 128 + scol;
      kldst[i] = (char*)Ksm + g * 32768 + c * 1024;
    }
  }
  // V bases: lane's d-rows (l31, l31+32), contiguous in kv
  const unsigned short* vb0 = vt + ((size_t)h * HD + l31) * N_TOK + g * 2048;
  const unsigned short* vb1 = vb0 + (size_t)32 * N_TOK;

  f32x16 oacc[2], fz;
#pragma unroll
  for (int r = 0; r < 16; ++r) { oacc[0][r] = 0.f; oacc[1][r] = 0.f; fz[r] = 0.f; }
  float lsp[4] = {0.f, 0.f, 0.f, 0.f};

  auto stageK = [&](int t) {
    gload16(kgsrc[0] + (size_t)t * 8192, kldst[0] + (t & 3) * 8192);
    gload16(kgsrc[1] + (size_t)t * 8192, kldst[1] + (t & 3) * 8192);
  };

  auto compute = [&](int t) {
    const char* KB  = kbase + (t & 3) * 8192;
    const int   kvo = t * 64;
    // V fragments direct from global (L2-hot); latency hides under QK MFMAs
    bf16x8 vr[2][4];
#pragma unroll
    for (int ks = 0; ks < 4; ++ks) {
      vr[0][ks] = *(const bf16x8*)(vb0 + kvo + ks * 16 + hi * 8);
      vr[1][ks] = *(const bf16x8*)(vb1 + kvo + ks * 16 + hi * 8);
    }
    // both QK^T streams (independent chains -> ILP)
    f32x16 sc[2];
    __builtin_amdgcn_s_setprio(1);
#pragma unroll
    for (int kt = 0; kt < 2; ++kt) {
      bf16x8 kf0 = *(const bf16x8*)(KB + kt * 4096 + slot[0]);
      sc[kt] = __builtin_amdgcn_mfma_f32_32x32x16_bf16(kf0, qf[0], fz, 0, 0, 0);
#pragma unroll
      for (int s = 1; s < 4; ++s) {
        bf16x8 kf = *(const bf16x8*)(KB + kt * 4096 + slot[s]);
        sc[kt] = __builtin_amdgcn_mfma_f32_32x32x16_bf16(kf, qf[s], sc[kt], 0, 0, 0);
      }
    }
    __builtin_amdgcn_s_setprio(0);
    // per-kt: exp2 (no shift), pack, PV
#pragma unroll
    for (int kt = 0; kt < 2; ++kt) {
      float e[16];
#pragma unroll
      for (int r = 0; r < 16; ++r) { e[r] = EXP2(sc[kt][r]); lsp[r & 3] += e[r]; }
      unsigned int wpk[4][2];
#pragma unroll
      for (int b = 0; b < 4; ++b) {
        wpk[b][0] = cvtpk(e[4*b+0], e[4*b+1]);
        wpk[b][1] = cvtpk(e[4*b+2], e[4*b+3]);
      }
#pragma unroll
      for (int pr = 0; pr < 2; ++pr) {
        unsigned int x0 = wpk[2*pr][0], x1 = wpk[2*pr][1];
        unsigned int y0 = wpk[2*pr+1][0], y1 = wpk[2*pr+1][1];
        plswap(x0, y0);
        plswap(x1, y1);
        union { unsigned int u[4]; bf16x8 v; } pa;
        pa.u[0] = x0; pa.u[1] = x1; pa.u[2] = y0; pa.u[3] = y1;
        const int ks = kt * 2 + pr;
        __builtin_amdgcn_s_setprio(1);
        oacc[0] = __builtin_amdgcn_mfma_f32_32x32x16_bf16(pa.v, vr[0][ks], oacc[0], 0, 0, 0);
        oacc[1] = __builtin_amdgcn_mfma_f32_32x32x16_bf16(pa.v, vr[1][ks], oacc[1], 0, 0, 0);
        __builtin_amdgcn_s_setprio(0);
      }
    }
  };

  // prologue: stage tiles 0,1
  stageK(0); stageK(1);
  __syncthreads();

  for (int p = 0; p < 16; ++p) {
    if (p < 15) { stageK(2 * p + 2); stageK(2 * p + 3); }
    compute(2 * p);
    compute(2 * p + 1);
    __syncthreads();   // closes reads of this pair's bufs (overwritten at p+1)
  }

  // ---- in-block merge of the two kv-groups via LDS, then bf16 write ----
  float ls = (lsp[0] + lsp[1]) + (lsp[2] + lsp[3]);
  ls += __shfl_xor(ls, 32);

  float* ex  = (float*)((char*)Ksm + 32768);   // 32 KB (group 1's K region)
  float* lsx = (float*)Ksm;                    // 1 KB (group 0's K region)
  const int idx = wv * 64 + lane;
  if (g == 1) {
#pragma unroll
    for (int dt = 0; dt < 2; ++dt)
#pragma unroll
      for (int r = 0; r < 16; ++r)
        ex[(dt * 16 + r) * 256 + idx] = oacc[dt][r];
    lsx[idx] = ls;
  }
  __syncthreads();
  if (g == 0) {
#pragma unroll
    for (int dt = 0; dt < 2; ++dt)
#pragma unroll
      for (int r = 0; r < 16; ++r)
        oacc[dt][r] += ex[(dt * 16 + r) * 256 + idx];
    ls += lsx[idx];
    float il = 1.f / ls;
#pragma unroll
    for (int r = 0; r < 16; ++r) {
      int q = (r & 3) + 8 * (r >> 2) + 4 * hi;
      float ilr = __int_as_float(
          __builtin_amdgcn_ds_bpermute(q << 2, __float_as_int(il)));
      unsigned short* op = ob + (size_t)(qbase + q) * DM + h * HD + l31;
      op[0]  = f2bf(oacc[0][r] * ilr);
      op[32] = f2bf(oacc[1][r] * ilr);
    }
  }
}

// ---------------- host ----------------
extern "C" void kernel_launch(void* const* d_in, const int* in_sizes, int n_in,
                              void* d_out, int out_size, void* d_ws, size_t ws_size,
                              hipStream_t stream) {
  const float* query = (const float*)d_in[0];
  const float* key   = (const float*)d_in[1];
  const float* value = (const float*)d_in[2];
  const float* Wq    = (const float*)d_in[3];
  const float* bq    = (const float*)d_in[4];
  const float* Wk    = (const float*)d_in[5];
  const float* bk    = (const float*)d_in[6];
  const float* Wv    = (const float*)d_in[7];
  const float* bv    = (const float*)d_in[8];
  const float* Wo    = (const float*)d_in[9];
  const float* bo    = (const float*)d_in[10];
  const float* qnw   = (const float*)d_in[11];
  const float* knw   = (const float*)d_in[12];

  char* ws = (char*)d_ws;
  const size_t MB = 1024 * 1024;
  unsigned short* qpj = (unsigned short*)(ws + 0 * MB);
  unsigned short* Kn  = (unsigned short*)(ws + 8 * MB);
  unsigned short* Vt  = (unsigned short*)(ws + 16 * MB);
  unsigned short* wob = (unsigned short*)(ws + 24 * MB);
  unsigned short* wqb = (unsigned short*)(ws + 26 * MB);
  unsigned short* wkb = (unsigned short*)(ws + 28 * MB);
  unsigned short* wvb = (unsigned short*)(ws + 30 * MB);
  unsigned short* qbf = (unsigned short*)(ws + 32 * MB);
  unsigned short* kbf = (unsigned short*)(ws + 40 * MB);
  unsigned short* vbf = (unsigned short*)(ws + 48 * MB);
  unsigned short* apj = (unsigned short*)(ws + 56 * MB);

  Cvt7 ca;
  ca.s[0] = query; ca.d[0] = qbf;
  ca.s[1] = key;   ca.d[1] = kbf;
  ca.s[2] = value; ca.d[2] = vbf;
  ca.s[3] = Wq;    ca.d[3] = wqb;
  ca.s[4] = Wk;    ca.d[4] = wkb;
  ca.s[5] = Wv;    ca.d[5] = wvb;
  ca.s[6] = Wo;    ca.d[6] = wob;
  cvt_all<<<2048, 256, 0, stream>>>(ca);

  qkv_gemm<<<dim3(DM / 128, N_TOK / 128, 3), 256, 0, stream>>>(
      qbf, kbf, vbf, wqb, wkb, wvb, bq, bk, bv, qpj, Kn, Vt, knw);

  attn_kernel<<<512, 512, 0, stream>>>(qpj, Kn, Vt, qnw, apj);

  out_gemm<<<dim3(DM / 128, N_TOK / 64), 256, 0, stream>>>(apj, wob, bo, (float*)d_out);
}

// Round 7
// 206.646 us; speedup vs baseline: 1.2775x; 1.2775x over previous
//
#include <hip/hip_runtime.h>
#include <stdint.h>
#include <stddef.h>

#define N_TOK 4096
#define DM    1024
#define NHEAD 16
#define HD    64

typedef __attribute__((ext_vector_type(8)))  short bf16x8;
typedef __attribute__((ext_vector_type(4)))  short bf16x4;
typedef __attribute__((ext_vector_type(4)))  float f32x4;
typedef __attribute__((ext_vector_type(16))) float f32x16;

static __device__ __forceinline__ float bf2f(short u) {
  union { unsigned int i; float f; } c;
  c.i = ((unsigned int)(unsigned short)u) << 16;
  return c.f;
}
static __device__ __forceinline__ unsigned short f2bf(float f) {
  union { float f; unsigned int i; } c; c.f = f;
  unsigned int x = c.i;
  return (unsigned short)((x + 0x7fffu + ((x >> 16) & 1u)) >> 16);
}
static __device__ __forceinline__ unsigned int cvtpk(float lo, float hi) {
  unsigned int d;
  asm("v_cvt_pk_bf16_f32 %0, %1, %2" : "=v"(d) : "v"(lo), "v"(hi));
  return d;
}
static __device__ __forceinline__ void plswap(unsigned int& a, unsigned int& b) {
  asm("v_permlane32_swap_b32 %0, %1" : "+v"(a), "+v"(b));
}
#if __has_builtin(__builtin_amdgcn_exp2f)
#define EXP2(x) __builtin_amdgcn_exp2f(x)
#else
#define EXP2(x) exp2f(x)
#endif
// async global->LDS, 16B/lane; LDS dest wave-uniform base (HW adds lane*16)
static __device__ __forceinline__ void gload16(const void* g, void* l) {
  __builtin_amdgcn_global_load_lds(
      (const __attribute__((address_space(1))) unsigned int*)g,
      (__attribute__((address_space(3))) unsigned int*)l, 16, 0, 0);
}

// ---------------- fused fp32 -> bf16 conversion (all 7 tensors, 1 launch) ----------------
struct Cvt7 { const float* s[7]; unsigned short* d[7]; };
__global__ void cvt_all(Cvt7 a) {
  int u0 = blockIdx.x << 10;              // 1024 units per block, uniform segment
  int seg, off;
  if (u0 < 1572864) { seg = u0 >> 19; off = u0 & 524287; }
  else { int j = u0 - 1572864; seg = 3 + (j >> 17); off = j & 131071; }
  const float* s = a.s[seg];
  unsigned short* dd = a.d[seg];
  int t = off + threadIdx.x;
#pragma unroll
  for (int j = 0; j < 4; ++j, t += 256) {
    const f32x4* sp = (const f32x4*)(s + (size_t)t * 8);
    f32x4 x = sp[0], y = sp[1];
    bf16x8 o;
    o[0] = (short)f2bf(x[0]); o[1] = (short)f2bf(x[1]);
    o[2] = (short)f2bf(x[2]); o[3] = (short)f2bf(x[3]);
    o[4] = (short)f2bf(y[0]); o[5] = (short)f2bf(y[1]);
    o[6] = (short)f2bf(y[2]); o[7] = (short)f2bf(y[3]);
    *(bf16x8*)(dd + (size_t)t * 8) = o;
  }
}

// ---------------- GEMM core: C = A @ W^T + bias, (MI*32)M x 128N tile, dbuf ----------------
// modes: 0 = bf16 row-major out; 1 = f32 row-major out;
//        2 = per-head RMSNorm -> Kn[h][n][64] bf16;  3 = transpose -> Vt[h][d][n] bf16
template <int MI>
static __device__ __forceinline__ void gemm_core(
    const unsigned short* __restrict__ A,
    const unsigned short* __restrict__ W,
    const float* __restrict__ bias,
    unsigned short* __restrict__ Cb,
    float* __restrict__ Cf,
    const float* __restrict__ nw,
    int Nn, int K, int mode, int m0, int n0)
{
  __shared__ __align__(16) unsigned short At[2][MI * 1024];  // (MI*32) x 32
  __shared__ __align__(16) unsigned short Wt[2][128 * 32];
  const int tid  = threadIdx.x;
  const int wid  = tid >> 6, lane = tid & 63;
  const int lm   = lane & 15, lg = lane >> 4;
  const int wm   = (wid >> 1) * (MI * 16), wn = (wid & 1) * 64;
  const int CPW  = (MI * 2 + 8) / 4;       // chunks per wave

  f32x4 acc[MI][4];
#pragma unroll
  for (int i = 0; i < MI; ++i)
#pragma unroll
    for (int j = 0; j < 4; ++j) acc[i][j] = f32x4{0.f, 0.f, 0.f, 0.f};

  auto stage = [&](int b, int k0) {
#pragma unroll
    for (int i = 0; i < CPW; ++i) {
      int c = wid * CPW + i;
      if (c < MI * 2)
        gload16(A + (size_t)(m0 + c * 16 + (lane >> 2)) * K + k0 + (lane & 3) * 8,
                (char*)At + b * (MI * 2048) + c * 1024);
      else
        gload16(W + (size_t)(n0 + (c - MI * 2) * 16 + (lane >> 2)) * K + k0 + (lane & 3) * 8,
                (char*)Wt + b * 8192 + (c - MI * 2) * 1024);
    }
  };

  const int nk = K >> 5;
  stage(0, 0);
  __syncthreads();
  for (int kt = 0; kt < nk; ++kt) {
    const int cur = kt & 1;
    if (kt + 1 < nk) stage(cur ^ 1, (kt + 1) << 5);

    bf16x8 af[MI], bfr[4];
#pragma unroll
    for (int mi = 0; mi < MI; ++mi)
      af[mi] = *(const bf16x8*)&At[cur][(wm + mi * 16 + lm) * 32 + lg * 8];
#pragma unroll
    for (int ni = 0; ni < 4; ++ni)
      bfr[ni] = *(const bf16x8*)&Wt[cur][(wn + ni * 16 + lm) * 32 + lg * 8];
    __builtin_amdgcn_s_setprio(1);
#pragma unroll
    for (int mi = 0; mi < MI; ++mi)
#pragma unroll
      for (int ni = 0; ni < 4; ++ni)
        acc[mi][ni] = __builtin_amdgcn_mfma_f32_16x16x32_bf16(
            af[mi], bfr[ni], acc[mi][ni], 0, 0, 0);
    __builtin_amdgcn_s_setprio(0);
    __syncthreads();
  }

  float bv[4];
#pragma unroll
  for (int ni = 0; ni < 4; ++ni) bv[ni] = bias[n0 + wn + ni * 16 + lm];

  if (mode <= 1) {
#pragma unroll
    for (int mi = 0; mi < MI; ++mi)
#pragma unroll
      for (int ni = 0; ni < 4; ++ni) {
        int n = n0 + wn + ni * 16 + lm;
#pragma unroll
        for (int r = 0; r < 4; ++r) {
          int m = m0 + wm + mi * 16 + lg * 4 + r;
          float v = acc[mi][ni][r] + bv[ni];
          if (mode == 1) Cf[(size_t)m * Nn + n] = v;
          else           Cb[(size_t)m * Nn + n] = f2bf(v);
        }
      }
  } else if (mode == 2) {
    // K path: wave's 64 cols = one full head; fused RMSNorm over d
    const int h = (n0 + wn) >> 6;
    float w_[4];
#pragma unroll
    for (int ni = 0; ni < 4; ++ni) w_[ni] = nw[ni * 16 + lm];
#pragma unroll
    for (int mi = 0; mi < MI; ++mi) {
      float t[4][4], ssq[4];
#pragma unroll
      for (int ni = 0; ni < 4; ++ni)
#pragma unroll
        for (int r = 0; r < 4; ++r) t[ni][r] = acc[mi][ni][r] + bv[ni];
#pragma unroll
      for (int r = 0; r < 4; ++r)
        ssq[r] = t[0][r]*t[0][r] + t[1][r]*t[1][r] + t[2][r]*t[2][r] + t[3][r]*t[3][r];
#pragma unroll
      for (int r = 0; r < 4; ++r) {
        ssq[r] += __shfl_xor(ssq[r], 1);
        ssq[r] += __shfl_xor(ssq[r], 2);
        ssq[r] += __shfl_xor(ssq[r], 4);
        ssq[r] += __shfl_xor(ssq[r], 8);
      }
#pragma unroll
      for (int r = 0; r < 4; ++r) {
        float iv = rsqrtf(ssq[r] * (1.f / 64.f) + 1e-5f);
        int n_ = m0 + wm + mi * 16 + lg * 4 + r;
#pragma unroll
        for (int ni = 0; ni < 4; ++ni) {
          int d = ni * 16 + lm;
          Cb[(size_t)h * (N_TOK * HD) + (size_t)n_ * HD + d] = f2bf(t[ni][r] * w_[ni] * iv);
        }
      }
    }
  } else {
    // V path: transpose to Vt[h][d][n]
    const int h = (n0 + wn) >> 6;
#pragma unroll
    for (int mi = 0; mi < MI; ++mi)
#pragma unroll
      for (int ni = 0; ni < 4; ++ni) {
        int d  = ni * 16 + lm;
        int nb = m0 + wm + mi * 16 + lg * 4;
        bf16x4 o;
#pragma unroll
        for (int r = 0; r < 4; ++r) o[r] = (short)f2bf(acc[mi][ni][r] + bv[ni]);
        *(bf16x4*)&Cb[(size_t)h * (HD * N_TOK) + (size_t)d * N_TOK + nb] = o;
      }
  }
}

// fused QKV projections: grid (8, 32, 3), 128x128 tiles, z selects {q,k,v}
__global__ __launch_bounds__(256, 3) void qkv_gemm(
    const unsigned short* __restrict__ a0, const unsigned short* __restrict__ a1,
    const unsigned short* __restrict__ a2,
    const unsigned short* __restrict__ w0, const unsigned short* __restrict__ w1,
    const unsigned short* __restrict__ w2,
    const float* __restrict__ b0, const float* __restrict__ b1,
    const float* __restrict__ b2,
    unsigned short* __restrict__ o0, unsigned short* __restrict__ o1,
    unsigned short* __restrict__ o2,
    const float* __restrict__ knw)
{
  const int z = blockIdx.z;
  const unsigned short* A = (z == 0) ? a0 : (z == 1) ? a1 : a2;
  const unsigned short* W = (z == 0) ? w0 : (z == 1) ? w1 : w2;
  const float* B          = (z == 0) ? b0 : (z == 1) ? b1 : b2;
  unsigned short* O       = (z == 0) ? o0 : (z == 1) ? o1 : o2;
  const int mode          = (z == 0) ? 0 : (z == 1) ? 2 : 3;
  gemm_core<4>(A, W, B, O, nullptr, knw, DM, DM, mode,
               blockIdx.y * 128, blockIdx.x * 128);
}

// out-projection: f32 out, 64x128 tiles, grid (8, 64)
__global__ __launch_bounds__(256, 4) void out_gemm(
    const unsigned short* __restrict__ A, const unsigned short* __restrict__ W,
    const float* __restrict__ bias, float* __restrict__ Cf)
{
  gemm_core<2>(A, W, bias, nullptr, Cf, nullptr, DM, DM, 1,
               blockIdx.y * 64, blockIdx.x * 128);
}

// ---------------- fused RMSNorm(Q) + attention: swapped-QK 32x32, in-block kv-split,
//                  K in LDS (dbuf), V loaded per-use from global (L2-hot) ----------
// grid 512 blocks x 512 threads. 8 waves = 2 kv-groups x 4 waves. q-tile 128/block.
// Softmax has NO max-shift: uniform scale cancels in P/sum(P); exp2 args bounded (<=93).
__global__ __launch_bounds__(512, 4) void attn_kernel(
    const unsigned short* __restrict__ qb,   // (n, 1024) bf16
    const unsigned short* __restrict__ kn,   // Kn[h][kv][64] bf16, normalized
    const unsigned short* __restrict__ vt,   // Vt[h][d][kv] bf16
    const float* __restrict__ wq,            // q_norm_w[64]
    unsigned short* __restrict__ ob)         // (n, 1024) bf16
{
  // K staging only: [group][buf][64x64 bf16 tile] = 32 KB; +1 KB ls exchange
  __shared__ __align__(16) unsigned short Ksm[2][2][4096];
  __shared__ float lsX[256];

  // XCD-aware decode: XCD x owns heads {2x, 2x+1}
  const int wg   = blockIdx.x;
  const int x_   = wg & 7, rest = wg >> 3;     // rest 0..63
  const int h    = x_ * 2 + (rest & 1);
  const int qt   = rest >> 1;                  // 0..31
  const int tid  = threadIdx.x;
  const int wid  = tid >> 6, lane = tid & 63;
  const int g    = wid >> 2, wv = wid & 3;
  const int l31  = lane & 31, hi = lane >> 5;
  const int sl   = l31 & 7;
  const int qbase = qt * 128 + wv * 32;

  // ---- Q fragments, RMSNorm fused, scaled by log2(e) ----
  bf16x8 qf[4];
  {
    const unsigned short* qp = qb + (size_t)(qbase + l31) * DM + h * HD + hi * 8;
    float qv[32]; float ss = 0.f;
#pragma unroll
    for (int s = 0; s < 4; ++s) {
      bf16x8 raw = *(const bf16x8*)(qp + s * 16);
#pragma unroll
      for (int j = 0; j < 8; ++j) { float f = bf2f(raw[j]); qv[s*8+j] = f; ss += f*f; }
    }
    ss += __shfl_xor(ss, 32);
    float inv = rsqrtf(ss * (1.f / 64.f) + 1e-5f) * 1.44269504f;
#pragma unroll
    for (int s = 0; s < 4; ++s)
#pragma unroll
      for (int j = 0; j < 8; ++j)
        qf[s][j] = (short)f2bf(qv[s*8+j] * wq[s*16 + hi*8 + j] * inv);
  }

  int slot[4];
#pragma unroll
  for (int x = 0; x < 4; ++x) slot[x] = (((2*x + hi) ^ sl) << 4);
  const char* kbase = (const char*)Ksm + g * 16384 + l31 * 128;

  // K staging: per wave 2 chunks of 1KB per tile (pre-swizzled global source)
  const char* kgsrc[2];
  char*       kldst[2];
  {
    const char* knb = (const char*)kn + (size_t)h * (N_TOK * HD * 2)
                    + (size_t)g * 2048 * 128;
#pragma unroll
    for (int i = 0; i < 2; ++i) {
      int c    = wv * 2 + i;            // chunk 0..7
      int off  = c * 1024 + lane * 16;
      int row  = off >> 7;              // kv-local row 0..63
      int scol = (off & 127) ^ ((row & 7) << 4);
      kgsrc[i] = knb + (size_t)row * 128 + scol;
      kldst[i] = (char*)Ksm + g * 16384 + c * 1024;
    }
  }
  // V bases: lane's d-rows (l31, l31+32), contiguous in kv (L2-resident per XCD)
  const unsigned short* vb0 = vt + ((size_t)h * HD + l31) * N_TOK + g * 2048;
  const unsigned short* vb1 = vb0 + (size_t)32 * N_TOK;

  f32x16 oacc[2], fz;
#pragma unroll
  for (int r = 0; r < 16; ++r) { oacc[0][r] = 0.f; oacc[1][r] = 0.f; fz[r] = 0.f; }
  float lsp[4] = {0.f, 0.f, 0.f, 0.f};

  // prologue: stage tile 0 into buf 0
  gload16(kgsrc[0], kldst[0]);
  gload16(kgsrc[1], kldst[1]);
  __syncthreads();

  const int NT = 2048 / 64;
  for (int it = 0; it < NT; ++it) {
    const int cur = it & 1;
    if (it + 1 < NT) {
      const int nb = cur ^ 1;
      gload16(kgsrc[0] + (size_t)(it + 1) * 8192, kldst[0] + nb * 8192);
      gload16(kgsrc[1] + (size_t)(it + 1) * 8192, kldst[1] + nb * 8192);
    }
    const char* KB  = kbase + cur * 8192;
    const int   kvo = it * 64;

#pragma unroll
    for (int kt = 0; kt < 2; ++kt) {
      // S^T = K Q^T over 32 kv x 32 q
      __builtin_amdgcn_s_setprio(1);
      bf16x8 kf0 = *(const bf16x8*)(KB + kt * 4096 + slot[0]);
      f32x16 sc = __builtin_amdgcn_mfma_f32_32x32x16_bf16(kf0, qf[0], fz, 0, 0, 0);
#pragma unroll
      for (int s = 1; s < 4; ++s) {
        bf16x8 kf = *(const bf16x8*)(KB + kt * 4096 + slot[s]);
        sc = __builtin_amdgcn_mfma_f32_32x32x16_bf16(kf, qf[s], sc, 0, 0, 0);
      }
      __builtin_amdgcn_s_setprio(0);
      // exp2 (no shift), pack, PV (V straight from global at point of use)
      float e[16];
#pragma unroll
      for (int r = 0; r < 16; ++r) { e[r] = EXP2(sc[r]); lsp[r & 3] += e[r]; }
      unsigned int wpk[4][2];
#pragma unroll
      for (int b = 0; b < 4; ++b) {
        wpk[b][0] = cvtpk(e[4*b+0], e[4*b+1]);
        wpk[b][1] = cvtpk(e[4*b+2], e[4*b+3]);
      }
#pragma unroll
      for (int pr = 0; pr < 2; ++pr) {
        unsigned int x0 = wpk[2*pr][0], x1 = wpk[2*pr][1];
        unsigned int y0 = wpk[2*pr+1][0], y1 = wpk[2*pr+1][1];
        plswap(x0, y0);
        plswap(x1, y1);
        union { unsigned int u[4]; bf16x8 v; } pa;
        pa.u[0] = x0; pa.u[1] = x1; pa.u[2] = y0; pa.u[3] = y1;
        const int ks = kt * 2 + pr;
        bf16x8 vf0 = *(const bf16x8*)(vb0 + kvo + ks * 16 + hi * 8);
        bf16x8 vf1 = *(const bf16x8*)(vb1 + kvo + ks * 16 + hi * 8);
        __builtin_amdgcn_s_setprio(1);
        oacc[0] = __builtin_amdgcn_mfma_f32_32x32x16_bf16(pa.v, vf0, oacc[0], 0, 0, 0);
        oacc[1] = __builtin_amdgcn_mfma_f32_32x32x16_bf16(pa.v, vf1, oacc[1], 0, 0, 0);
        __builtin_amdgcn_s_setprio(0);
      }
    }
    __syncthreads();
  }

  // ---- in-block merge of the two kv-groups via LDS, then bf16 write ----
  float ls = (lsp[0] + lsp[1]) + (lsp[2] + lsp[3]);
  ls += __shfl_xor(ls, 32);

  float* ex = (float*)Ksm;   // 32 KB = 8192 floats, exactly the exchange size
  const int idx = wv * 64 + lane;
  if (g == 1) {
#pragma unroll
    for (int dt = 0; dt < 2; ++dt)
#pragma unroll
      for (int r = 0; r < 16; ++r)
        ex[(dt * 16 + r) * 256 + idx] = oacc[dt][r];
    lsX[idx] = ls;
  }
  __syncthreads();
  if (g == 0) {
#pragma unroll
    for (int dt = 0; dt < 2; ++dt)
#pragma unroll
      for (int r = 0; r < 16; ++r)
        oacc[dt][r] += ex[(dt * 16 + r) * 256 + idx];
    ls += lsX[idx];
    float il = 1.f / ls;
#pragma unroll
    for (int r = 0; r < 16; ++r) {
      int q = (r & 3) + 8 * (r >> 2) + 4 * hi;
      float ilr = __int_as_float(
          __builtin_amdgcn_ds_bpermute(q << 2, __float_as_int(il)));
      unsigned short* op = ob + (size_t)(qbase + q) * DM + h * HD + l31;
      op[0]  = f2bf(oacc[0][r] * ilr);
      op[32] = f2bf(oacc[1][r] * ilr);
    }
  }
}

// ---------------- host ----------------
extern "C" void kernel_launch(void* const* d_in, const int* in_sizes, int n_in,
                              void* d_out, int out_size, void* d_ws, size_t ws_size,
                              hipStream_t stream) {
  const float* query = (const float*)d_in[0];
  const float* key   = (const float*)d_in[1];
  const float* value = (const float*)d_in[2];
  const float* Wq    = (const float*)d_in[3];
  const float* bq    = (const float*)d_in[4];
  const float* Wk    = (const float*)d_in[5];
  const float* bk    = (const float*)d_in[6];
  const float* Wv    = (const float*)d_in[7];
  const float* bv    = (const float*)d_in[8];
  const float* Wo    = (const float*)d_in[9];
  const float* bo    = (const float*)d_in[10];
  const float* qnw   = (const float*)d_in[11];
  const float* knw   = (const float*)d_in[12];

  char* ws = (char*)d_ws;
  const size_t MB = 1024 * 1024;
  unsigned short* qpj = (unsigned short*)(ws + 0 * MB);
  unsigned short* Kn  = (unsigned short*)(ws + 8 * MB);
  unsigned short* Vt  = (unsigned short*)(ws + 16 * MB);
  unsigned short* wob = (unsigned short*)(ws + 24 * MB);
  unsigned short* wqb = (unsigned short*)(ws + 26 * MB);
  unsigned short* wkb = (unsigned short*)(ws + 28 * MB);
  unsigned short* wvb = (unsigned short*)(ws + 30 * MB);
  unsigned short* qbf = (unsigned short*)(ws + 32 * MB);
  unsigned short* kbf = (unsigned short*)(ws + 40 * MB);
  unsigned short* vbf = (unsigned short*)(ws + 48 * MB);
  unsigned short* apj = (unsigned short*)(ws + 56 * MB);

  Cvt7 ca;
  ca.s[0] = query; ca.d[0] = qbf;
  ca.s[1] = key;   ca.d[1] = kbf;
  ca.s[2] = value; ca.d[2] = vbf;
  ca.s[3] = Wq;    ca.d[3] = wqb;
  ca.s[4] = Wk;    ca.d[4] = wkb;
  ca.s[5] = Wv;    ca.d[5] = wvb;
  ca.s[6] = Wo;    ca.d[6] = wob;
  cvt_all<<<2048, 256, 0, stream>>>(ca);

  qkv_gemm<<<dim3(DM / 128, N_TOK / 128, 3), 256, 0, stream>>>(
      qbf, kbf, vbf, wqb, wkb, wvb, bq, bk, bv, qpj, Kn, Vt, knw);

  attn_kernel<<<512, 512, 0, stream>>>(qpj, Kn, Vt, qnw, apj);

  out_gemm<<<dim3(DM / 128, N_TOK / 64), 256, 0, stream>>>(apj, wob, bo, (float*)d_out);
}

// Round 8
// 152.187 us; speedup vs baseline: 1.7346x; 1.3578x over previous
//
#include <hip/hip_runtime.h>
#include <stdint.h>
#include <stddef.h>

#define N_TOK 4096
#define DM    1024
#define NHEAD 16
#define HD    64

typedef __attribute__((ext_vector_type(8)))  short bf16x8;
typedef __attribute__((ext_vector_type(4)))  short bf16x4;
typedef __attribute__((ext_vector_type(4)))  float f32x4;
typedef __attribute__((ext_vector_type(16))) float f32x16;

static __device__ __forceinline__ float bf2f(short u) {
  union { unsigned int i; float f; } c;
  c.i = ((unsigned int)(unsigned short)u) << 16;
  return c.f;
}
static __device__ __forceinline__ unsigned short f2bf(float f) {
  union { float f; unsigned int i; } c; c.f = f;
  unsigned int x = c.i;
  return (unsigned short)((x + 0x7fffu + ((x >> 16) & 1u)) >> 16);
}
static __device__ __forceinline__ unsigned int cvtpk(float lo, float hi) {
  unsigned int d;
  asm("v_cvt_pk_bf16_f32 %0, %1, %2" : "=v"(d) : "v"(lo), "v"(hi));
  return d;
}
static __device__ __forceinline__ void plswap(unsigned int& a, unsigned int& b) {
  asm("v_permlane32_swap_b32 %0, %1" : "+v"(a), "+v"(b));
}
#if __has_builtin(__builtin_amdgcn_exp2f)
#define EXP2(x) __builtin_amdgcn_exp2f(x)
#else
#define EXP2(x) exp2f(x)
#endif
// async global->LDS, 16B/lane; LDS dest wave-uniform base (HW adds lane*16)
static __device__ __forceinline__ void gload16(const void* g, void* l) {
  __builtin_amdgcn_global_load_lds(
      (const __attribute__((address_space(1))) unsigned int*)g,
      (__attribute__((address_space(3))) unsigned int*)l, 16, 0, 0);
}

// ---------------- fused fp32 -> bf16 conversion (all 7 tensors, 1 launch) ----------------
struct Cvt7 { const float* s[7]; unsigned short* d[7]; };
__global__ void cvt_all(Cvt7 a) {
  int u0 = blockIdx.x << 10;              // 1024 units per block, uniform segment
  int seg, off;
  if (u0 < 1572864) { seg = u0 >> 19; off = u0 & 524287; }
  else { int j = u0 - 1572864; seg = 3 + (j >> 17); off = j & 131071; }
  const float* s = a.s[seg];
  unsigned short* dd = a.d[seg];
  int t = off + threadIdx.x;
#pragma unroll
  for (int j = 0; j < 4; ++j, t += 256) {
    const f32x4* sp = (const f32x4*)(s + (size_t)t * 8);
    f32x4 x = sp[0], y = sp[1];
    bf16x8 o;
    o[0] = (short)f2bf(x[0]); o[1] = (short)f2bf(x[1]);
    o[2] = (short)f2bf(x[2]); o[3] = (short)f2bf(x[3]);
    o[4] = (short)f2bf(y[0]); o[5] = (short)f2bf(y[1]);
    o[6] = (short)f2bf(y[2]); o[7] = (short)f2bf(y[3]);
    *(bf16x8*)(dd + (size_t)t * 8) = o;
  }
}

// ---------------- GEMM core: C = A @ W^T + bias, (MI*32)M x 128N tile, dbuf ----------------
// modes: 0 = bf16 row-major out; 1 = f32 row-major out;
//        2 = per-head RMSNorm -> Kn[h][n][64] bf16;  3 = transpose -> Vt[h][d][n] bf16
template <int MI>
static __device__ __forceinline__ void gemm_core(
    const unsigned short* __restrict__ A,
    const unsigned short* __restrict__ W,
    const float* __restrict__ bias,
    unsigned short* __restrict__ Cb,
    float* __restrict__ Cf,
    const float* __restrict__ nw,
    int Nn, int K, int mode, int m0, int n0)
{
  __shared__ __align__(16) unsigned short At[2][MI * 1024];  // (MI*32) x 32
  __shared__ __align__(16) unsigned short Wt[2][128 * 32];
  const int tid  = threadIdx.x;
  const int wid  = tid >> 6, lane = tid & 63;
  const int lm   = lane & 15, lg = lane >> 4;
  const int wm   = (wid >> 1) * (MI * 16), wn = (wid & 1) * 64;
  const int CPW  = (MI * 2 + 8) / 4;       // chunks per wave

  f32x4 acc[MI][4];
#pragma unroll
  for (int i = 0; i < MI; ++i)
#pragma unroll
    for (int j = 0; j < 4; ++j) acc[i][j] = f32x4{0.f, 0.f, 0.f, 0.f};

  auto stage = [&](int b, int k0) {
#pragma unroll
    for (int i = 0; i < CPW; ++i) {
      int c = wid * CPW + i;
      if (c < MI * 2)
        gload16(A + (size_t)(m0 + c * 16 + (lane >> 2)) * K + k0 + (lane & 3) * 8,
                (char*)At + b * (MI * 2048) + c * 1024);
      else
        gload16(W + (size_t)(n0 + (c - MI * 2) * 16 + (lane >> 2)) * K + k0 + (lane & 3) * 8,
                (char*)Wt + b * 8192 + (c - MI * 2) * 1024);
    }
  };

  const int nk = K >> 5;
  stage(0, 0);
  __syncthreads();
  for (int kt = 0; kt < nk; ++kt) {
    const int cur = kt & 1;
    if (kt + 1 < nk) stage(cur ^ 1, (kt + 1) << 5);

    bf16x8 af[MI], bfr[4];
#pragma unroll
    for (int mi = 0; mi < MI; ++mi)
      af[mi] = *(const bf16x8*)&At[cur][(wm + mi * 16 + lm) * 32 + lg * 8];
#pragma unroll
    for (int ni = 0; ni < 4; ++ni)
      bfr[ni] = *(const bf16x8*)&Wt[cur][(wn + ni * 16 + lm) * 32 + lg * 8];
    __builtin_amdgcn_s_setprio(1);
#pragma unroll
    for (int mi = 0; mi < MI; ++mi)
#pragma unroll
      for (int ni = 0; ni < 4; ++ni)
        acc[mi][ni] = __builtin_amdgcn_mfma_f32_16x16x32_bf16(
            af[mi], bfr[ni], acc[mi][ni], 0, 0, 0);
    __builtin_amdgcn_s_setprio(0);
    __syncthreads();
  }

  float bv[4];
#pragma unroll
  for (int ni = 0; ni < 4; ++ni) bv[ni] = bias[n0 + wn + ni * 16 + lm];

  if (mode <= 1) {
#pragma unroll
    for (int mi = 0; mi < MI; ++mi)
#pragma unroll
      for (int ni = 0; ni < 4; ++ni) {
        int n = n0 + wn + ni * 16 + lm;
#pragma unroll
        for (int r = 0; r < 4; ++r) {
          int m = m0 + wm + mi * 16 + lg * 4 + r;
          float v = acc[mi][ni][r] + bv[ni];
          if (mode == 1) Cf[(size_t)m * Nn + n] = v;
          else           Cb[(size_t)m * Nn + n] = f2bf(v);
        }
      }
  } else if (mode == 2) {
    // K path: wave's 64 cols = one full head; fused RMSNorm over d
    const int h = (n0 + wn) >> 6;
    float w_[4];
#pragma unroll
    for (int ni = 0; ni < 4; ++ni) w_[ni] = nw[ni * 16 + lm];
#pragma unroll
    for (int mi = 0; mi < MI; ++mi) {
      float t[4][4], ssq[4];
#pragma unroll
      for (int ni = 0; ni < 4; ++ni)
#pragma unroll
        for (int r = 0; r < 4; ++r) t[ni][r] = acc[mi][ni][r] + bv[ni];
#pragma unroll
      for (int r = 0; r < 4; ++r)
        ssq[r] = t[0][r]*t[0][r] + t[1][r]*t[1][r] + t[2][r]*t[2][r] + t[3][r]*t[3][r];
#pragma unroll
      for (int r = 0; r < 4; ++r) {
        ssq[r] += __shfl_xor(ssq[r], 1);
        ssq[r] += __shfl_xor(ssq[r], 2);
        ssq[r] += __shfl_xor(ssq[r], 4);
        ssq[r] += __shfl_xor(ssq[r], 8);
      }
#pragma unroll
      for (int r = 0; r < 4; ++r) {
        float iv = rsqrtf(ssq[r] * (1.f / 64.f) + 1e-5f);
        int n_ = m0 + wm + mi * 16 + lg * 4 + r;
#pragma unroll
        for (int ni = 0; ni < 4; ++ni) {
          int d = ni * 16 + lm;
          Cb[(size_t)h * (N_TOK * HD) + (size_t)n_ * HD + d] = f2bf(t[ni][r] * w_[ni] * iv);
        }
      }
    }
  } else {
    // V path: transpose to Vt[h][d][n]
    const int h = (n0 + wn) >> 6;
#pragma unroll
    for (int mi = 0; mi < MI; ++mi)
#pragma unroll
      for (int ni = 0; ni < 4; ++ni) {
        int d  = ni * 16 + lm;
        int nb = m0 + wm + mi * 16 + lg * 4;
        bf16x4 o;
#pragma unroll
        for (int r = 0; r < 4; ++r) o[r] = (short)f2bf(acc[mi][ni][r] + bv[ni]);
        *(bf16x4*)&Cb[(size_t)h * (HD * N_TOK) + (size_t)d * N_TOK + nb] = o;
      }
  }
}

// fused QKV projections: grid (8, 32, 3), 128x128 tiles, z selects {q,k,v}
__global__ __launch_bounds__(256, 3) void qkv_gemm(
    const unsigned short* __restrict__ a0, const unsigned short* __restrict__ a1,
    const unsigned short* __restrict__ a2,
    const unsigned short* __restrict__ w0, const unsigned short* __restrict__ w1,
    const unsigned short* __restrict__ w2,
    const float* __restrict__ b0, const float* __restrict__ b1,
    const float* __restrict__ b2,
    unsigned short* __restrict__ o0, unsigned short* __restrict__ o1,
    unsigned short* __restrict__ o2,
    const float* __restrict__ knw)
{
  const int z = blockIdx.z;
  const unsigned short* A = (z == 0) ? a0 : (z == 1) ? a1 : a2;
  const unsigned short* W = (z == 0) ? w0 : (z == 1) ? w1 : w2;
  const float* B          = (z == 0) ? b0 : (z == 1) ? b1 : b2;
  unsigned short* O       = (z == 0) ? o0 : (z == 1) ? o1 : o2;
  const int mode          = (z == 0) ? 0 : (z == 1) ? 2 : 3;
  gemm_core<4>(A, W, B, O, nullptr, knw, DM, DM, mode,
               blockIdx.y * 128, blockIdx.x * 128);
}

// out-projection: f32 out, 128x128 tiles, grid (8, 32)
__global__ __launch_bounds__(256, 3) void out_gemm(
    const unsigned short* __restrict__ A, const unsigned short* __restrict__ W,
    const float* __restrict__ bias, float* __restrict__ Cf)
{
  gemm_core<4>(A, W, bias, nullptr, Cf, nullptr, DM, DM, 1,
               blockIdx.y * 128, blockIdx.x * 128);
}

// ---------------- fused RMSNorm(Q) + attention, swapped-QK 32x32, in-block kv-split ----------------
// grid 512 blocks x 512 threads. 8 waves = 2 kv-groups x 4 waves. q-tile 128/block.
// Softmax uses NO max-shift: uniform scale cancels in P/sum(P); args bounded (|s'|<=93).
__global__ __launch_bounds__(512, 4) void attn_kernel(
    const unsigned short* __restrict__ qb,   // (n, 1024) bf16
    const unsigned short* __restrict__ kn,   // Kn[h][kv][64] bf16, normalized
    const unsigned short* __restrict__ vt,   // Vt[h][d][kv] bf16
    const float* __restrict__ wq,            // q_norm_w[64]
    unsigned short* __restrict__ ob)         // (n, 1024) bf16
{
  // [group][buf][K/V][4096 bf16]: 64 KB total
  __shared__ __align__(16) unsigned short SM[2][2][2][4096];

  // XCD-aware decode: XCD x owns heads {2x, 2x+1}
  const int wg   = blockIdx.x;
  const int x_   = wg & 7, rest = wg >> 3;     // rest 0..63
  const int h    = x_ * 2 + (rest & 1);
  const int qt   = rest >> 1;                  // 0..31
  const int tid  = threadIdx.x;
  const int wid  = tid >> 6, lane = tid & 63;
  const int g    = wid >> 2, wv = wid & 3;
  const int l31  = lane & 31, hi = lane >> 5;
  const int sl   = l31 & 7;
  const int qbase = qt * 128 + wv * 32;

  // ---- Q fragments, RMSNorm fused, scaled by log2(e) ----
  bf16x8 qf[4];
  {
    const unsigned short* qp = qb + (size_t)(qbase + l31) * DM + h * HD + hi * 8;
    float qv[32]; float ss = 0.f;
#pragma unroll
    for (int s = 0; s < 4; ++s) {
      bf16x8 raw = *(const bf16x8*)(qp + s * 16);
#pragma unroll
      for (int j = 0; j < 8; ++j) { float f = bf2f(raw[j]); qv[s*8+j] = f; ss += f*f; }
    }
    ss += __shfl_xor(ss, 32);
    float inv = rsqrtf(ss * (1.f / 64.f) + 1e-5f) * 1.44269504f;
#pragma unroll
    for (int s = 0; s < 4; ++s)
#pragma unroll
      for (int j = 0; j < 8; ++j)
        qf[s][j] = (short)f2bf(qv[s*8+j] * wq[s*16 + hi*8 + j] * inv);
  }

  int slot[4];
#pragma unroll
  for (int x = 0; x < 4; ++x) slot[x] = (((2*x + hi) ^ sl) << 4);
  const char* base = (const char*)SM + g * 32768 + l31 * 128;

  // staging sources (pre-swizzled global addresses), 4 chunks/wave within group
  const char* gsrc[4];
  char*       ldst[4];
  long        gstep[4];
  {
    const char* knb = (const char*)kn + (size_t)h * (N_TOK * HD * 2);
    const char* vtb = (const char*)vt + (size_t)h * (HD * N_TOK * 2);
    char* smG = (char*)SM + g * 32768;   // buf 0 of this group
#pragma unroll
    for (int i = 0; i < 4; ++i) {
      int chunk = wv * 4 + i;            // 0..7 K, 8..15 V
      int off   = (chunk & 7) * 1024 + lane * 16;
      int row   = off >> 7;
      int scol  = (off & 127) ^ ((row & 7) << 4);
      if (chunk < 8) {
        gsrc[i]  = knb + (size_t)(g * 2048 + row) * 128 + scol;
        gstep[i] = 64 * 128;
        ldst[i]  = smG + (chunk & 7) * 1024;
      } else {
        gsrc[i]  = vtb + (size_t)row * (N_TOK * 2) + g * 4096 + scol;
        gstep[i] = 64 * 2;
        ldst[i]  = smG + 8192 + (chunk & 7) * 1024;
      }
    }
  }

  f32x16 oacc[2], fz;
#pragma unroll
  for (int r = 0; r < 16; ++r) { oacc[0][r] = 0.f; oacc[1][r] = 0.f; fz[r] = 0.f; }
  float lsp[4] = {0.f, 0.f, 0.f, 0.f};

  // prologue: stage tile 0 into buf 0
#pragma unroll
  for (int i = 0; i < 4; ++i) { gload16(gsrc[i], ldst[i]); gsrc[i] += gstep[i]; }
  __syncthreads();

  const int NT = 2048 / 64;
  for (int it = 0; it < NT; ++it) {
    const int cur = it & 1;
    if (it + 1 < NT) {
      const int nb = cur ^ 1;
#pragma unroll
      for (int i = 0; i < 4; ++i) {
        gload16(gsrc[i], ldst[i] + nb * 16384);
        gsrc[i] += gstep[i];
      }
    }
    const char* KB = base + cur * 16384;
    const char* VB = KB + 8192;

#pragma unroll
    for (int kt = 0; kt < 2; ++kt) {
      // S^T = K Q^T over 32 kv x 32 q
      __builtin_amdgcn_s_setprio(1);
      bf16x8 kf0 = *(const bf16x8*)(KB + kt * 4096 + slot[0]);
      f32x16 sc = __builtin_amdgcn_mfma_f32_32x32x16_bf16(kf0, qf[0], fz, 0, 0, 0);
#pragma unroll
      for (int s = 1; s < 4; ++s) {
        bf16x8 kf = *(const bf16x8*)(KB + kt * 4096 + slot[s]);
        sc = __builtin_amdgcn_mfma_f32_32x32x16_bf16(kf, qf[s], sc, 0, 0, 0);
      }
      __builtin_amdgcn_s_setprio(0);
      // exp2 (no shift), pack, PV
      float e[16];
#pragma unroll
      for (int r = 0; r < 16; ++r) { e[r] = EXP2(sc[r]); lsp[r & 3] += e[r]; }
      unsigned int wpk[4][2];
#pragma unroll
      for (int b = 0; b < 4; ++b) {
        wpk[b][0] = cvtpk(e[4*b+0], e[4*b+1]);
        wpk[b][1] = cvtpk(e[4*b+2], e[4*b+3]);
      }
#pragma unroll
      for (int pr = 0; pr < 2; ++pr) {
        unsigned int x0 = wpk[2*pr][0], x1 = wpk[2*pr][1];
        unsigned int y0 = wpk[2*pr+1][0], y1 = wpk[2*pr+1][1];
        plswap(x0, y0);
        plswap(x1, y1);
        union { unsigned int u[4]; bf16x8 v; } pa;
        pa.u[0] = x0; pa.u[1] = x1; pa.u[2] = y0; pa.u[3] = y1;
        int ks = kt * 2 + pr;
        __builtin_amdgcn_s_setprio(1);
#pragma unroll
        for (int dt = 0; dt < 2; ++dt) {
          bf16x8 vf = *(const bf16x8*)(VB + dt * 4096 + slot[ks]);
          oacc[dt] = __builtin_amdgcn_mfma_f32_32x32x16_bf16(pa.v, vf, oacc[dt], 0, 0, 0);
        }
        __builtin_amdgcn_s_setprio(0);
      }
    }
    __syncthreads();
  }

  // ---- in-block merge of the two kv-groups via LDS, then bf16 write ----
  float ls = (lsp[0] + lsp[1]) + (lsp[2] + lsp[3]);
  ls += __shfl_xor(ls, 32);

  float* ex  = (float*)((char*)SM + 32768);   // 32 KB (group 1's region)
  float* lsx = (float*)SM;                    // 1 KB (group 0's region)
  const int idx = wv * 64 + lane;
  if (g == 1) {
#pragma unroll
    for (int dt = 0; dt < 2; ++dt)
#pragma unroll
      for (int r = 0; r < 16; ++r)
        ex[(dt * 16 + r) * 256 + idx] = oacc[dt][r];
    lsx[idx] = ls;
  }
  __syncthreads();
  if (g == 0) {
#pragma unroll
    for (int dt = 0; dt < 2; ++dt)
#pragma unroll
      for (int r = 0; r < 16; ++r)
        oacc[dt][r] += ex[(dt * 16 + r) * 256 + idx];
    ls += lsx[idx];
    float il = 1.f / ls;
#pragma unroll
    for (int r = 0; r < 16; ++r) {
      int q = (r & 3) + 8 * (r >> 2) + 4 * hi;
      float ilr = __int_as_float(
          __builtin_amdgcn_ds_bpermute(q << 2, __float_as_int(il)));
      unsigned short* op = ob + (size_t)(qbase + q) * DM + h * HD + l31;
      op[0]  = f2bf(oacc[0][r] * ilr);
      op[32] = f2bf(oacc[1][r] * ilr);
    }
  }
}

// ---------------- host ----------------
extern "C" void kernel_launch(void* const* d_in, const int* in_sizes, int n_in,
                              void* d_out, int out_size, void* d_ws, size_t ws_size,
                              hipStream_t stream) {
  const float* query = (const float*)d_in[0];
  const float* key   = (const float*)d_in[1];
  const float* value = (const float*)d_in[2];
  const float* Wq    = (const float*)d_in[3];
  const float* bq    = (const float*)d_in[4];
  const float* Wk    = (const float*)d_in[5];
  const float* bk    = (const float*)d_in[6];
  const float* Wv    = (const float*)d_in[7];
  const float* bv    = (const float*)d_in[8];
  const float* Wo    = (const float*)d_in[9];
  const float* bo    = (const float*)d_in[10];
  const float* qnw   = (const float*)d_in[11];
  const float* knw   = (const float*)d_in[12];

  char* ws = (char*)d_ws;
  const size_t MB = 1024 * 1024;
  unsigned short* qpj = (unsigned short*)(ws + 0 * MB);
  unsigned short* Kn  = (unsigned short*)(ws + 8 * MB);
  unsigned short* Vt  = (unsigned short*)(ws + 16 * MB);
  unsigned short* wob = (unsigned short*)(ws + 24 * MB);
  unsigned short* wqb = (unsigned short*)(ws + 26 * MB);
  unsigned short* wkb = (unsigned short*)(ws + 28 * MB);
  unsigned short* wvb = (unsigned short*)(ws + 30 * MB);
  unsigned short* qbf = (unsigned short*)(ws + 32 * MB);
  unsigned short* kbf = (unsigned short*)(ws + 40 * MB);
  unsigned short* vbf = (unsigned short*)(ws + 48 * MB);
  unsigned short* apj = (unsigned short*)(ws + 56 * MB);

  Cvt7 ca;
  ca.s[0] = query; ca.d[0] = qbf;
  ca.s[1] = key;   ca.d[1] = kbf;
  ca.s[2] = value; ca.d[2] = vbf;
  ca.s[3] = Wq;    ca.d[3] = wqb;
  ca.s[4] = Wk;    ca.d[4] = wkb;
  ca.s[5] = Wv;    ca.d[5] = wvb;
  ca.s[6] = Wo;    ca.d[6] = wob;
  cvt_all<<<2048, 256, 0, stream>>>(ca);

  qkv_gemm<<<dim3(DM / 128, N_TOK / 128, 3), 256, 0, stream>>>(
      qbf, kbf, vbf, wqb, wkb, wvb, bq, bk, bv, qpj, Kn, Vt, knw);

  attn_kernel<<<512, 512, 0, stream>>>(qpj, Kn, Vt, qnw, apj);

  out_gemm<<<dim3(DM / 128, N_TOK / 128), 256, 0, stream>>>(apj, wob, bo, (float*)d_out);
}